// Round 1
// baseline (179.496 us; speedup 1.0000x reference)
//
#include <hip/hip_runtime.h>
#include <hip/hip_bf16.h>
#include <stdint.h>

// Problem constants
#define B_  2
#define S_  2048
#define D_  1024
#define H_  16
#define DQ_ 64
#define QT_ (S_/64)   // 32 q-tiles per (b,h)
#define FMAX_ 16.0f   // fixed softmax max: logits ~ N(0,1)/sqrt64 -> max ~5.5 << 16

// exp(x*0.125 - FMAX) == exp2(x*C1 + C0)
#define C1_ 0.18033688011112042f   // 0.125 * log2(e)
#define C0_ (-23.083120654223414f) // -16  * log2(e)

typedef float f32x4 __attribute__((ext_vector_type(4)));
typedef short bf16x8 __attribute__((ext_vector_type(8)));

__device__ __forceinline__ unsigned short f2bf(float f) {
    uint32_t u = __float_as_uint(f);
    u += 0x7fffu + ((u >> 16) & 1u);   // round-to-nearest-even
    return (unsigned short)(u >> 16);
}
__device__ __forceinline__ float bf2f(unsigned short u) {
    return __uint_as_float(((uint32_t)u) << 16);
}
__device__ __forceinline__ bf16x8 packbf8(float4 a, float4 b) {
    bf16x8 r;
    r[0]=(short)f2bf(a.x); r[1]=(short)f2bf(a.y);
    r[2]=(short)f2bf(a.z); r[3]=(short)f2bf(a.w);
    r[4]=(short)f2bf(b.x); r[5]=(short)f2bf(b.y);
    r[6]=(short)f2bf(b.z); r[7]=(short)f2bf(b.w);
    return r;
}
__device__ __forceinline__ float fast_exp2(float x) {
#if __has_builtin(__builtin_amdgcn_exp2f)
    return __builtin_amdgcn_exp2f(x);
#else
    float r; asm("v_exp_f32 %0, %1" : "=v"(r) : "v"(x)); return r;
#endif
}
__device__ __forceinline__ uint32_t cvt_pk_bf16(float lo, float hi) {
    uint32_t r;
    asm("v_cvt_pk_bf16_f32 %0, %1, %2" : "=v"(r) : "v"(lo), "v"(hi));
    return r;
}

// ---------------------------------------------------------------------------
// Kernel 1: prep — K fp32->bf16, Wo fp32->bf16, V transpose->bf16 (+Pv
// column partials for the row-0 mean(V) path). One launch, 6144 blocks:
//   [0,1024)      : V transpose (st = blk&31, h = (blk>>5)&15, b = blk>>9)
//   [1024,5120)   : K convert   (float4 granules)
//   [5120,6144)   : Wo convert
// ---------------------------------------------------------------------------
__global__ __launch_bounds__(256) void prep_kernel(
    const float* __restrict__ K, const float* __restrict__ V,
    const float* __restrict__ W,
    unsigned short* __restrict__ Kb, unsigned short* __restrict__ Vt,
    unsigned short* __restrict__ Wb, float* __restrict__ Pv)
{
    __shared__ unsigned short Ls[64][72];
    const int blk = blockIdx.x, tid = threadIdx.x;

    if (blk < 1024) {
        const int st = blk & 31, h = (blk >> 5) & 15, b = blk >> 9;
        {
            int row = tid >> 2, col0 = (tid & 3) * 16;   // row=s-in-tile, col=dq
            const float* src = V + (((size_t)b*S_ + (size_t)st*64 + row)*D_ + h*64 + col0);
            float4 f0 = ((const float4*)src)[0];
            float4 f1 = ((const float4*)src)[1];
            float4 f2 = ((const float4*)src)[2];
            float4 f3 = ((const float4*)src)[3];
            unsigned short* d = &Ls[row][col0];
            d[0]=f2bf(f0.x); d[1]=f2bf(f0.y); d[2]=f2bf(f0.z); d[3]=f2bf(f0.w);
            d[4]=f2bf(f1.x); d[5]=f2bf(f1.y); d[6]=f2bf(f1.z); d[7]=f2bf(f1.w);
            d[8]=f2bf(f2.x); d[9]=f2bf(f2.y); d[10]=f2bf(f2.z); d[11]=f2bf(f2.w);
            d[12]=f2bf(f3.x); d[13]=f2bf(f3.y); d[14]=f2bf(f3.z); d[15]=f2bf(f3.w);
        }
        __syncthreads();
        {
            int d = tid >> 2, scol = (tid & 3) * 16;     // d = dq row of Vt
            unsigned short tmp[16];
            float psum = 0.f;
            #pragma unroll
            for (int i = 0; i < 16; ++i) {
                unsigned short u = Ls[scol + i][d];
                tmp[i] = u;
                psum += bf2f(u);
            }
            unsigned short* dst = Vt + ((size_t)((b*H_ + h)*64 + d)*S_ + st*64 + scol);
            ((uint4*)dst)[0] = *((uint4*)tmp);
            ((uint4*)dst)[1] = *((uint4*)(tmp + 8));
            psum += __shfl_xor(psum, 1);
            psum += __shfl_xor(psum, 2);
            if ((tid & 3) == 0)
                Pv[((size_t)(b*H_ + h)*64 + d)*32 + st] = psum;
        }
    } else if (blk < 5120) {
        int i = (blk - 1024)*256 + tid;     // < B*S*D/4 = 1048576
        float4 f = ((const float4*)K)[i];
        ushort4 o;
        o.x = f2bf(f.x); o.y = f2bf(f.y); o.z = f2bf(f.z); o.w = f2bf(f.w);
        ((ushort4*)Kb)[i] = o;
    } else {
        int i = (blk - 5120)*256 + tid;     // < D*D/4 = 262144
        float4 f = ((const float4*)W)[i];
        ushort4 o;
        o.x = f2bf(f.x); o.y = f2bf(f.y); o.z = f2bf(f.z); o.w = f2bf(f.w);
        ((ushort4*)Wb)[i] = o;
    }
}

// ---------------------------------------------------------------------------
// Kernel 2: flash attention. Fixed-max softmax. LDS-traffic-minimized:
//  - QK^T computed TRANSPOSED (S^T = mfma(K_frag, Q_frag)): lane holds 4
//    consecutive keys of one q-row -> P packed with v_cvt_pk_bf16_f32 and
//    written as 4x ds_write_b64/iter (was 16x scattered ds_write_b16).
//  - V fragments read DIRECTLY from global Vtb ([d][key] layout is fragment
//    perfect); all 4 waves read identical addresses -> L1 hit; per-head V
//    (256KB bf16) lives in the XCD's L2 via the bid%8 swizzle. Removes the
//    Vts staging writes + 8 ds_read_b128/wave-iter from the LDS pipe.
//  - K stays LDS-staged (balances DS pipe vs TA/L1 pipe).
// Block = 256 thr (4 waves, 16 q-rows each), two q-tiles {pa, 31-pa} per
// block = 33 K-tile iters. Grid 512: bid = g + 32*pa, g = h + 16*b; all 16
// pa-blocks of a head share bid%8 -> same XCD L2.
// Row q=0 (fully masked -> uniform = mean(V)) computed from Pv by pa==0.
// ---------------------------------------------------------------------------
__global__ __launch_bounds__(256, 2) void attn_kernel(
    const float* __restrict__ Q,
    const unsigned short* __restrict__ Kb,
    const unsigned short* __restrict__ Vtb,
    const float* __restrict__ Pv,
    unsigned short* __restrict__ ctx,
    const int* __restrict__ maskp)
{
    __shared__ unsigned short Ks [2][64][72];   // [buf][key][dq]
    __shared__ unsigned short Ps [4][16][72];   // per-wave P: [q][key]

    const int bid = blockIdx.x;
    const int g = bid & 31, pa = bid >> 5;      // g = h + 16*b
    const int h = g & 15, b = g >> 4;
    const int tid  = threadIdx.x;
    const int wave = tid >> 6, lane = tid & 63;
    const int quad = lane >> 4, ln = lane & 15;
    const int maskv = maskp[0];

    // fused mean(V) -> ctx row 0, cols [h*64, h*64+64)
    if (maskv && pa == 0 && tid < 64) {
        const float* p = Pv + ((size_t)(b*H_ + h)*64 + tid)*32;
        float s = 0.f;
        #pragma unroll
        for (int i = 0; i < 32; ++i) s += p[i];
        ctx[(size_t)b*S_*D_ + h*64 + tid] = f2bf(s * (1.0f/S_));
    }

    const int srow = tid >> 2, scol = (tid & 3)*16;
    const unsigned short* kbase =
        Kb + (((size_t)b*S_ + srow)*D_ + h*64 + scol);          // + j*64*D_
    // per-lane V fragment base: row d = nt*16 + ln, key col = j*64 + quad*8
    const unsigned short* vfb =
        Vtb + ((size_t)((b*H_ + h)*64 + ln))*S_ + quad*8;

    const int ql = wave*16 + ln;   // this lane's q row (within q-tile)

    for (int t = 0; t < 2; ++t) {
        const int qt = t ? (QT_-1 - pa) : pa;
        const int niter = maskv ? (qt + 1) : QT_;

        // Q fragments: fp32 global -> bf16 registers (read once)
        const float* qrow =
            Q + (((size_t)b*S_ + (size_t)qt*64 + wave*16 + ln)*D_ + h*64);
        float4 q0 = ((const float4*)(qrow + quad*8))[0];
        float4 q1 = ((const float4*)(qrow + quad*8))[1];
        float4 q2 = ((const float4*)(qrow + 32 + quad*8))[0];
        float4 q3 = ((const float4*)(qrow + 32 + quad*8))[1];
        bf16x8 aq0 = packbf8(q0, q1);
        bf16x8 aq1 = packbf8(q2, q3);

        // prefetch K tile 0
        uint4 k0 = *((const uint4*)(kbase));
        uint4 k1 = *((const uint4*)(kbase + 8));

        f32x4 o[4] = {};
        float lsum = 0.f;
        const int qg = qt*64 + wave*16 + quad*4;   // + r = global q row (epilogue)

        if (t) __syncthreads();   // protect Ks buffers from previous pass

        for (int j = 0; j < niter; ++j) {
            const int cur = j & 1;
            *((uint4*)&Ks[cur][srow][scol])   = k0;
            *((uint4*)&Ks[cur][srow][scol+8]) = k1;
            uint4 nk0, nk1;
            if (j + 1 < niter) {
                const unsigned short* kp = kbase + (size_t)(j+1)*64*D_;
                nk0 = *((const uint4*)(kp));
                nk1 = *((const uint4*)(kp + 8));
            }
            // V fragments straight from global (issued early; latency hides
            // under the barrier + QK^T + softmax below)
            bf16x8 vf[4][2];
            {
                const unsigned short* vjb = vfb + j*64;
                #pragma unroll
                for (int nt = 0; nt < 4; ++nt) {
                    vf[nt][0] = *(const bf16x8*)(vjb + nt*16*S_);
                    vf[nt][1] = *(const bf16x8*)(vjb + nt*16*S_ + 32);
                }
            }
            __syncthreads();

            // ---- S^T = K Q^T : s[nt][r] = S[key = nt*16+quad*4+r][q = ln] ----
            f32x4 s[4] = {};
            #pragma unroll
            for (int nt = 0; nt < 4; ++nt) {
                bf16x8 b0 = *(const bf16x8*)&Ks[cur][nt*16 + ln][quad*8];
                bf16x8 b1 = *(const bf16x8*)&Ks[cur][nt*16 + ln][32 + quad*8];
                s[nt] = __builtin_amdgcn_mfma_f32_16x16x32_bf16(b0, aq0, s[nt], 0,0,0);
                s[nt] = __builtin_amdgcn_mfma_f32_16x16x32_bf16(b1, aq1, s[nt], 0,0,0);
            }

            // ---- P = exp2(C1*S + C0); accumulate l; pack -> Ps[q][key] ----
            if (maskv && j == qt) {
                #pragma unroll
                for (int nt = 0; nt < 4; ++nt) {
                    const int kl = nt*16 + quad*4;   // key local (this lane, r=0)
                    float e0 = (kl+0 >= ql) ? 0.f : fast_exp2(fmaf(s[nt][0], C1_, C0_));
                    float e1 = (kl+1 >= ql) ? 0.f : fast_exp2(fmaf(s[nt][1], C1_, C0_));
                    float e2 = (kl+2 >= ql) ? 0.f : fast_exp2(fmaf(s[nt][2], C1_, C0_));
                    float e3 = (kl+3 >= ql) ? 0.f : fast_exp2(fmaf(s[nt][3], C1_, C0_));
                    lsum += (e0+e1)+(e2+e3);
                    uint2 pk;
                    pk.x = cvt_pk_bf16(e0, e1);
                    pk.y = cvt_pk_bf16(e2, e3);
                    *((uint2*)&Ps[wave][ln][nt*16 + quad*4]) = pk;
                }
            } else {
                #pragma unroll
                for (int nt = 0; nt < 4; ++nt) {
                    float e0 = fast_exp2(fmaf(s[nt][0], C1_, C0_));
                    float e1 = fast_exp2(fmaf(s[nt][1], C1_, C0_));
                    float e2 = fast_exp2(fmaf(s[nt][2], C1_, C0_));
                    float e3 = fast_exp2(fmaf(s[nt][3], C1_, C0_));
                    lsum += (e0+e1)+(e2+e3);
                    uint2 pk;
                    pk.x = cvt_pk_bf16(e0, e1);
                    pk.y = cvt_pk_bf16(e2, e3);
                    *((uint2*)&Ps[wave][ln][nt*16 + quad*4]) = pk;
                }
            }
            // no barrier: Ps is per-wave; DS pipe is in-order per wave

            // ---- O += P V ----
            {
                bf16x8 a0 = *(const bf16x8*)&Ps[wave][ln][quad*8];
                bf16x8 a1 = *(const bf16x8*)&Ps[wave][ln][32 + quad*8];
                #pragma unroll
                for (int nt = 0; nt < 4; ++nt) {
                    o[nt] = __builtin_amdgcn_mfma_f32_16x16x32_bf16(a0, vf[nt][0], o[nt], 0,0,0);
                    o[nt] = __builtin_amdgcn_mfma_f32_16x16x32_bf16(a1, vf[nt][1], o[nt], 0,0,0);
                }
            }
            k0 = nk0; k1 = nk1;
        }

        // ---- epilogue: reduce l over the 4 quads, write ctx = O/l ----
        // lane holds partial sum for q = ql; quads hold disjoint key subsets
        lsum += __shfl_xor(lsum, 16);
        lsum += __shfl_xor(lsum, 32);
        float invl = 1.0f / lsum;
        float inv[4];
        #pragma unroll
        for (int r = 0; r < 4; ++r)
            inv[r] = __shfl(invl, quad*4 + r);   // inv for q = qg + r
        #pragma unroll
        for (int nt = 0; nt < 4; ++nt)
            #pragma unroll
            for (int r = 0; r < 4; ++r) {
                int q = qg + r;
                if (maskv && q == 0) continue;   // row 0 = mean(V), done above
                int c = h*64 + nt*16 + ln;
                ctx[((size_t)b*S_ + q)*D_ + c] = f2bf(o[nt][r]*inv[r]);
            }
        __syncthreads();   // before next pass re-writes Ks buffers
    }
}

// ---------------------------------------------------------------------------
// Kernel 3: out = ctx @ Wo^T + bias   (M=4096, N=1024, K=1024, bf16 MFMA)
// 64x128 tile, 4 waves (each 64x32), BK=64, double-buffered, 1 barrier/kt.
// Grid (8, 64) = 512 blocks -> 2 blocks/CU; bid%8 = nt0 -> each XCD caches
// exactly one 128-col Wo panel (0.25 MB).
// ---------------------------------------------------------------------------
__global__ __launch_bounds__(256, 2) void proj_kernel(
    const unsigned short* __restrict__ A,    // ctx bf16 [4096][1024]
    const unsigned short* __restrict__ Bw,   // Wo bf16  [1024][1024]
    const float* __restrict__ bias,
    float* __restrict__ out)
{
    __shared__ unsigned short As[2][64][72];
    __shared__ unsigned short Bs[2][128][72];
    const int nt0 = blockIdx.x;   // 0..7   (N panel)
    const int mt0 = blockIdx.y;   // 0..63  (M panel)
    const int tid  = threadIdx.x;
    const int wave = tid >> 6, lane = tid & 63;
    const int quad = lane >> 4, ln = lane & 15;

    const int arow = tid >> 2, acol = (tid & 3)*16;   // A: 64 rows x 64 cols
    const int brow = tid >> 1, bcol = (tid & 1)*32;   // B: 128 rows x 64 cols
    const unsigned short* aptr = A  + ((size_t)(mt0*64  + arow)*1024 + acol);
    const unsigned short* bptr = Bw + ((size_t)(nt0*128 + brow)*1024 + bcol);

    uint4 a0 = ((const uint4*)aptr)[0], a1 = ((const uint4*)aptr)[1];
    uint4 b0 = ((const uint4*)bptr)[0], b1 = ((const uint4*)bptr)[1],
          b2 = ((const uint4*)bptr)[2], b3 = ((const uint4*)bptr)[3];

    f32x4 acc[4][2] = {};

    for (int kt = 0; kt < 16; ++kt) {
        const int cur = kt & 1;
        *((uint4*)&As[cur][arow][acol])    = a0;
        *((uint4*)&As[cur][arow][acol+8])  = a1;
        *((uint4*)&Bs[cur][brow][bcol])    = b0;
        *((uint4*)&Bs[cur][brow][bcol+8])  = b1;
        *((uint4*)&Bs[cur][brow][bcol+16]) = b2;
        *((uint4*)&Bs[cur][brow][bcol+24]) = b3;
        uint4 na0, na1, nb0, nb1, nb2, nb3;
        if (kt < 15) {
            const unsigned short* ap = aptr + (kt+1)*64;
            const unsigned short* bp = bptr + (kt+1)*64;
            na0 = ((const uint4*)ap)[0]; na1 = ((const uint4*)ap)[1];
            nb0 = ((const uint4*)bp)[0]; nb1 = ((const uint4*)bp)[1];
            nb2 = ((const uint4*)bp)[2]; nb3 = ((const uint4*)bp)[3];
        }
        __syncthreads();
        #pragma unroll
        for (int ks = 0; ks < 2; ++ks) {
            bf16x8 am[4], bn[2];
            #pragma unroll
            for (int i = 0; i < 4; ++i)
                am[i] = *(const bf16x8*)&As[cur][i*16 + ln][ks*32 + quad*8];
            #pragma unroll
            for (int i = 0; i < 2; ++i)
                bn[i] = *(const bf16x8*)&Bs[cur][wave*32 + i*16 + ln][ks*32 + quad*8];
            #pragma unroll
            for (int mi = 0; mi < 4; ++mi)
                #pragma unroll
                for (int ni = 0; ni < 2; ++ni)
                    acc[mi][ni] = __builtin_amdgcn_mfma_f32_16x16x32_bf16(
                        am[mi], bn[ni], acc[mi][ni], 0,0,0);
        }
        a0 = na0; a1 = na1;
        b0 = nb0; b1 = nb1; b2 = nb2; b3 = nb3;
    }

    #pragma unroll
    for (int mi = 0; mi < 4; ++mi)
        #pragma unroll
        for (int ni = 0; ni < 2; ++ni) {
            int row = mt0*64 + mi*16 + quad*4;
            int col = nt0*128 + wave*32 + ni*16 + ln;
            float bv = bias[col];
            #pragma unroll
            for (int r = 0; r < 4; ++r)
                out[(size_t)(row + r)*1024 + col] = acc[mi][ni][r] + bv;
        }
}

// ---------------------------------------------------------------------------
extern "C" void kernel_launch(void* const* d_in, const int* in_sizes, int n_in,
                              void* d_out, int out_size, void* d_ws, size_t ws_size,
                              hipStream_t stream)
{
    const float* Q   = (const float*)d_in[0];
    const float* K   = (const float*)d_in[1];
    const float* V   = (const float*)d_in[2];
    const float* Wo  = (const float*)d_in[3];
    const float* Wb  = (const float*)d_in[4];
    const int* maskp = (const int*)d_in[5];
    float* out = (float*)d_out;

    // workspace layout (ushort units)
    unsigned short* Kb   = (unsigned short*)d_ws;
    unsigned short* Vtb  = Kb  + (size_t)B_*S_*D_;
    unsigned short* Wob  = Vtb + (size_t)B_*S_*D_;
    unsigned short* ctxb = Wob + (size_t)D_*D_;
    float* Pv = (float*)(ctxb + (size_t)B_*S_*D_);   // [B*H*64][32] partials
    // total: 3*8.39MB + 2.10MB + 0.26MB = ~27.6 MB

    prep_kernel<<<6144, 256, 0, stream>>>(K, V, Wo, Kb, Vtb, Wob, Pv);
    attn_kernel<<<512, 256, 0, stream>>>(Q, Kb, Vtb, Pv, ctxb, maskp);
    proj_kernel<<<dim3(8, 64), 256, 0, stream>>>(ctxb, Wob, Wb, out);
}

// Round 2
// 148.328 us; speedup vs baseline: 1.2101x; 1.2101x over previous
//
#include <hip/hip_runtime.h>
#include <hip/hip_bf16.h>
#include <stdint.h>

// Problem constants
#define B_  2
#define S_  2048
#define D_  1024
#define H_  16
#define DQ_ 64
#define QT_ (S_/64)   // 32 q-tiles (64 rows each) per (b,h)
#define FMAX_ 16.0f   // fixed softmax max: logits ~ N(0,1)/sqrt64 -> max ~5.5 << 16

// exp(x*0.125 - FMAX) == exp2(x*C1 + C0)
#define C1_ 0.18033688011112042f   // 0.125 * log2(e)
#define C0_ (-23.083120654223414f) // -16  * log2(e)

typedef float f32x4  __attribute__((ext_vector_type(4)));
typedef float f32x16 __attribute__((ext_vector_type(16)));
typedef short bf16x8 __attribute__((ext_vector_type(8)));

__device__ __forceinline__ unsigned short f2bf(float f) {
    uint32_t u = __float_as_uint(f);
    u += 0x7fffu + ((u >> 16) & 1u);   // round-to-nearest-even
    return (unsigned short)(u >> 16);
}
__device__ __forceinline__ bf16x8 packbf8(float4 a, float4 b) {
    bf16x8 r;
    r[0]=(short)f2bf(a.x); r[1]=(short)f2bf(a.y);
    r[2]=(short)f2bf(a.z); r[3]=(short)f2bf(a.w);
    r[4]=(short)f2bf(b.x); r[5]=(short)f2bf(b.y);
    r[6]=(short)f2bf(b.z); r[7]=(short)f2bf(b.w);
    return r;
}
__device__ __forceinline__ float fast_exp2(float x) {
#if __has_builtin(__builtin_amdgcn_exp2f)
    return __builtin_amdgcn_exp2f(x);
#else
    float r; asm("v_exp_f32 %0, %1" : "=v"(r) : "v"(x)); return r;
#endif
}
__device__ __forceinline__ uint32_t cvt_pk_bf16(float lo, float hi) {
    uint32_t r;
    asm("v_cvt_pk_bf16_f32 %0, %1, %2" : "=v"(r) : "v"(lo), "v"(hi));
    return r;
}
// vdst[32..63] <-> vsrc[0..31]
__device__ __forceinline__ void permlane32_swap(uint32_t &a, uint32_t &b) {
    asm volatile("v_permlane32_swap_b32 %0, %1" : "+v"(a), "+v"(b));
}

// ---------------------------------------------------------------------------
// Kernel 1: prep. Emits K and V in EXACT 32x32x16-MFMA fragment order so the
// attention kernel's loads are perfectly coalesced (frag = 64 lanes x 16B
// contiguous). Also Wo fp32->bf16 and Pv column partials (row-0 mean(V)).
// Grid 3072 x 256:
//   [0,1024)    : Vf fragments + Pv   (g = blk>>5, j = blk&31)
//   [1024,2048) : Kf fragments
//   [2048,3072) : Wo convert
// Kf frag fb = wk*4+s : lane l holds K[j*64+wk*32+(l&31)][s*16+(l>>5)*8 + 0..7]
// Vf frag fb = s*2+kk : lane l holds V[j*64+s*16+(l>>5)*8 + 0..7][kk*32+(l&31)]
// ---------------------------------------------------------------------------
__global__ __launch_bounds__(256) void prep_kernel(
    const float* __restrict__ K, const float* __restrict__ V,
    const float* __restrict__ W,
    unsigned short* __restrict__ Kf, unsigned short* __restrict__ Vf,
    unsigned short* __restrict__ Wb, float* __restrict__ Pv)
{
    __shared__ float Pp[4][64];
    const int blk = blockIdx.x, tid = threadIdx.x;

    if (blk < 1024) {
        const int g = blk >> 5, j = blk & 31;
        const int b = g >> 4, h = g & 15;
        float psum = 0.f;
        #pragma unroll
        for (int ps = 0; ps < 2; ++ps) {
            const int slot = tid + ps*256;
            const int fb = slot >> 6, l = slot & 63;
            const int s = fb >> 1, kk = fb & 1;
            const int hi = l >> 5, l31 = l & 31;
            const float* src = V + ((size_t)(b*S_ + j*64 + s*16 + hi*8))*D_
                                 + h*64 + kk*32 + l31;
            unsigned short us[8];
            #pragma unroll
            for (int r = 0; r < 8; ++r) {
                float v = src[(size_t)r*D_];
                psum += v;
                us[r] = f2bf(v);
            }
            *(uint4*)(Vf + ((size_t)(g*32 + j)*8 + fb)*512 + (size_t)l*8) = *(uint4*)us;
        }
        {   // reduce psum over the 4 threads sharing d = kk*32+l31
            const int fb = tid >> 6, l = tid & 63;
            const int kk = fb & 1, s01 = (fb >> 1) & 1;
            const int hi = l >> 5, l31 = l & 31;
            Pp[s01*2 + hi][kk*32 + l31] = psum;
        }
        __syncthreads();
        if (tid < 64) {
            float t = Pp[0][tid] + Pp[1][tid] + Pp[2][tid] + Pp[3][tid];
            Pv[((size_t)g*64 + tid)*32 + j] = t;
        }
    } else if (blk < 2048) {
        const int gb = blk - 1024;
        const int g = gb >> 5, j = gb & 31;
        const int b = g >> 4, h = g & 15;
        #pragma unroll
        for (int ps = 0; ps < 2; ++ps) {
            const int slot = tid + ps*256;
            const int fb = slot >> 6, l = slot & 63;
            const int wk = fb >> 2, s = fb & 3;
            const int hi = l >> 5, l31 = l & 31;
            const float* src = K + ((size_t)(b*S_ + j*64 + wk*32 + l31))*D_
                                 + h*64 + s*16 + hi*8;
            float4 f0 = ((const float4*)src)[0];
            float4 f1 = ((const float4*)src)[1];
            unsigned short us[8];
            us[0]=f2bf(f0.x); us[1]=f2bf(f0.y); us[2]=f2bf(f0.z); us[3]=f2bf(f0.w);
            us[4]=f2bf(f1.x); us[5]=f2bf(f1.y); us[6]=f2bf(f1.z); us[7]=f2bf(f1.w);
            *(uint4*)(Kf + ((size_t)(g*32 + j)*8 + fb)*512 + (size_t)l*8) = *(uint4*)us;
        }
    } else {
        int i = (blk - 2048)*256 + tid;     // < D*D/4 = 262144
        float4 f = ((const float4*)W)[i];
        ushort4 o;
        o.x = f2bf(f.x); o.y = f2bf(f.y); o.z = f2bf(f.z); o.w = f2bf(f.w);
        ((ushort4*)Wb)[i] = o;
    }
}

// ---------------------------------------------------------------------------
// Kernel 2: flash attention, 32x32x16 MFMA, ZERO-LDS main loop.
// Block = 256 thr = 4 waves: wave (wq,wk) owns q-rows [wq*32,+32) x keys
// [wk*32,+32) of each 64-key tile. K/V fragments loaded straight from the
// prearranged Kf/Vf (coalesced 1KB/instr), P kept in-register via
// cvt_pk_bf16 + v_permlane32_swap_b32. No barriers inside the j-loop; each
// wave uses its own niter (fully-masked diagonal waves skip free).
// Cross-wk O/l reduction through LDS once per pass.
// Grid 512: g = bid&31 (h + 16*b), pa = bid>>5 in [0,16); in-block pass
// pairing {pa, 31-pa} -> 33 iters/block, uniform. bid%8 = g%8 -> all blocks
// of a head-group on one XCD (K/V/Q ~1MB/group stays in L2).
// Row q=0 (fully masked -> mean(V)) from Pv by pa==0.
// ---------------------------------------------------------------------------
__global__ __launch_bounds__(256, 2) void attn_kernel(
    const float* __restrict__ Q,
    const unsigned short* __restrict__ Kf,
    const unsigned short* __restrict__ Vf,
    const float* __restrict__ Pv,
    unsigned short* __restrict__ ctx,
    const int* __restrict__ maskp)
{
    __shared__ float Osum[2][32][68];   // [wq][q][d] partial O from wk=1
    __shared__ float Lsum[2][32];       // [wq][q]    partial l from wk=1

    const int bid = blockIdx.x;
    const int g = bid & 31, pa = bid >> 5;
    const int h = g & 15, b = g >> 4;
    const int tid  = threadIdx.x;
    const int wave = tid >> 6, lane = tid & 63;
    const int wq = wave >> 1, wk = wave & 1;
    const int hi = lane >> 5, l31 = lane & 31;
    const int maskv = maskp[0];

    // fused mean(V) -> ctx row 0, cols [h*64, h*64+64)
    if (maskv && pa == 0 && tid < 64) {
        const float* p = Pv + ((size_t)g*64 + tid)*32;
        float s = 0.f;
        #pragma unroll
        for (int i = 0; i < 32; ++i) s += p[i];
        ctx[(size_t)b*S_*D_ + h*64 + tid] = f2bf(s * (1.0f/S_));
    }

    // fragment bases (advance by j*8*512 per tile)
    const unsigned short* kfb =
        Kf + ((size_t)g*32*8 + wk*4)*512 + (size_t)lane*8;
    const unsigned short* vfb =
        Vf + ((size_t)g*32*8 + wk*4)*512 + (size_t)lane*8;

    for (int t = 0; t < 2; ++t) {
        const int qt = t ? (31 - pa) : pa;
        int njw = maskv ? (qt + 1) : QT_;
        if (maskv && wq == 0 && wk == 1) njw = qt;  // diagonal tile fully masked

        // Q fragments: fp32 global -> bf16 registers (read once per pass)
        const int q0 = qt*64 + wq*32 + l31;
        const float* qrow = Q + ((size_t)(b*S_ + q0))*D_ + h*64;
        bf16x8 qf[4];
        #pragma unroll
        for (int s = 0; s < 4; ++s) {
            float4 f0 = ((const float4*)(qrow + s*16 + hi*8))[0];
            float4 f1 = ((const float4*)(qrow + s*16 + hi*8))[1];
            qf[s] = packbf8(f0, f1);
        }

        f32x16 o[2] = {};          // o[kk2]: d-halves of wave's 32q x 64d
        float lsum = 0.f;

        bf16x8 kc[4], vc[4], kn[4], vn[4];
        const unsigned short* kfj = kfb;
        const unsigned short* vfj = vfb;
        if (njw > 0) {
            #pragma unroll
            for (int s = 0; s < 4; ++s) {
                kc[s] = *(const bf16x8*)(kfj + s*512);
                vc[s] = *(const bf16x8*)(vfj + s*512);
            }
        }

        for (int j = 0; j < njw; ++j) {
            if (j + 1 < njw) {
                const unsigned short* kp = kfj + 8*512;
                const unsigned short* vp = vfj + 8*512;
                #pragma unroll
                for (int s = 0; s < 4; ++s) {
                    kn[s] = *(const bf16x8*)(kp + s*512);
                    vn[s] = *(const bf16x8*)(vp + s*512);
                }
            }

            // ---- S^T = K Q^T : lane holds col q=l31, rows key=(r&3)+8*(r>>2)+4*hi
            f32x16 st = {};
            #pragma unroll
            for (int s = 0; s < 4; ++s)
                st = __builtin_amdgcn_mfma_f32_32x32x16_bf16(kc[s], qf[s], st, 0,0,0);

            // ---- P = exp2(C1*S + C0), diagonal mask, accumulate l ----
            const bool diag = maskv && (j == qt) && (wk == wq);
            float e[16];
            #pragma unroll
            for (int r = 0; r < 16; ++r) {
                float ev = fast_exp2(fmaf(st[r], C1_, C0_));
                if (diag) {
                    int kr = (r&3) + 8*(r>>2) + 4*hi;   // key off == q off frame
                    ev = (kr >= l31) ? 0.f : ev;
                }
                e[r] = ev;
                lsum += ev;
            }

            // ---- pack P -> A-fragments in-register (cvt_pk + permlane swaps)
            uint32_t p01 = cvt_pk_bf16(e[0], e[1]);
            uint32_t p23 = cvt_pk_bf16(e[2], e[3]);
            uint32_t p45 = cvt_pk_bf16(e[4], e[5]);
            uint32_t p67 = cvt_pk_bf16(e[6], e[7]);
            permlane32_swap(p01, p45);
            permlane32_swap(p23, p67);
            uint32_t r01 = cvt_pk_bf16(e[8],  e[9]);
            uint32_t r23 = cvt_pk_bf16(e[10], e[11]);
            uint32_t r45 = cvt_pk_bf16(e[12], e[13]);
            uint32_t r67 = cvt_pk_bf16(e[14], e[15]);
            permlane32_swap(r01, r45);
            permlane32_swap(r23, r67);
            union { uint32_t u[4]; bf16x8 v; } pa0, pa1;
            pa0.u[0]=p01; pa0.u[1]=p23; pa0.u[2]=p45; pa0.u[3]=p67;  // keys 0..15
            pa1.u[0]=r01; pa1.u[1]=r23; pa1.u[2]=r45; pa1.u[3]=r67;  // keys 16..31

            // ---- O += P V ----
            o[0] = __builtin_amdgcn_mfma_f32_32x32x16_bf16(pa0.v, vc[0], o[0], 0,0,0);
            o[1] = __builtin_amdgcn_mfma_f32_32x32x16_bf16(pa0.v, vc[1], o[1], 0,0,0);
            o[0] = __builtin_amdgcn_mfma_f32_32x32x16_bf16(pa1.v, vc[2], o[0], 0,0,0);
            o[1] = __builtin_amdgcn_mfma_f32_32x32x16_bf16(pa1.v, vc[3], o[1], 0,0,0);

            #pragma unroll
            for (int s = 0; s < 4; ++s) { kc[s] = kn[s]; vc[s] = vn[s]; }
            kfj += 8*512; vfj += 8*512;
        }

        // ---- cross-wk reduction + epilogue ----
        lsum += __shfl_xor(lsum, 32);   // combine hi/lo key quads: l for q=l31

        if (wk == 1) {
            #pragma unroll
            for (int r = 0; r < 16; ++r) {
                int qr = (r&3) + 8*(r>>2) + 4*hi;
                Osum[wq][qr][l31]      = o[0][r];
                Osum[wq][qr][32 + l31] = o[1][r];
            }
            if (hi == 0) Lsum[wq][l31] = lsum;
        }
        __syncthreads();
        if (wk == 0) {
            float inv = 1.0f / (lsum + Lsum[wq][l31]);   // inv for q = l31
            #pragma unroll
            for (int r = 0; r < 16; ++r) {
                int qr = (r&3) + 8*(r>>2) + 4*hi;
                float o0v = o[0][r] + Osum[wq][qr][l31];
                float o1v = o[1][r] + Osum[wq][qr][32 + l31];
                float invr = __shfl(inv, qr);
                int q = qt*64 + wq*32 + qr;
                if (!(maskv && q == 0)) {   // row 0 = mean(V), done above
                    size_t base = ((size_t)(b*S_ + q))*D_ + h*64;
                    ctx[base + l31]      = f2bf(o0v * invr);
                    ctx[base + 32 + l31] = f2bf(o1v * invr);
                }
            }
        }
        __syncthreads();   // Osum/Lsum reused next pass
    }
}

// ---------------------------------------------------------------------------
// Kernel 3: out = ctx @ Wo^T + bias   (M=4096, N=1024, K=1024, bf16 MFMA)
// 64x128 tile, 4 waves (each 64x32), BK=64, double-buffered, 1 barrier/kt.
// Grid (8, 64) = 512 blocks -> 2 blocks/CU; bid%8 = nt0 -> each XCD caches
// exactly one 128-col Wo panel (0.25 MB).
// ---------------------------------------------------------------------------
__global__ __launch_bounds__(256, 2) void proj_kernel(
    const unsigned short* __restrict__ A,    // ctx bf16 [4096][1024]
    const unsigned short* __restrict__ Bw,   // Wo bf16  [1024][1024]
    const float* __restrict__ bias,
    float* __restrict__ out)
{
    __shared__ unsigned short As[2][64][72];
    __shared__ unsigned short Bs[2][128][72];
    const int nt0 = blockIdx.x;   // 0..7   (N panel)
    const int mt0 = blockIdx.y;   // 0..63  (M panel)
    const int tid  = threadIdx.x;
    const int wave = tid >> 6, lane = tid & 63;
    const int quad = lane >> 4, ln = lane & 15;

    const int arow = tid >> 2, acol = (tid & 3)*16;   // A: 64 rows x 64 cols
    const int brow = tid >> 1, bcol = (tid & 1)*32;   // B: 128 rows x 64 cols
    const unsigned short* aptr = A  + ((size_t)(mt0*64  + arow)*1024 + acol);
    const unsigned short* bptr = Bw + ((size_t)(nt0*128 + brow)*1024 + bcol);

    uint4 a0 = ((const uint4*)aptr)[0], a1 = ((const uint4*)aptr)[1];
    uint4 b0 = ((const uint4*)bptr)[0], b1 = ((const uint4*)bptr)[1],
          b2 = ((const uint4*)bptr)[2], b3 = ((const uint4*)bptr)[3];

    f32x4 acc[4][2] = {};

    for (int kt = 0; kt < 16; ++kt) {
        const int cur = kt & 1;
        *((uint4*)&As[cur][arow][acol])    = a0;
        *((uint4*)&As[cur][arow][acol+8])  = a1;
        *((uint4*)&Bs[cur][brow][bcol])    = b0;
        *((uint4*)&Bs[cur][brow][bcol+8])  = b1;
        *((uint4*)&Bs[cur][brow][bcol+16]) = b2;
        *((uint4*)&Bs[cur][brow][bcol+24]) = b3;
        uint4 na0, na1, nb0, nb1, nb2, nb3;
        if (kt < 15) {
            const unsigned short* ap = aptr + (kt+1)*64;
            const unsigned short* bp = bptr + (kt+1)*64;
            na0 = ((const uint4*)ap)[0]; na1 = ((const uint4*)ap)[1];
            nb0 = ((const uint4*)bp)[0]; nb1 = ((const uint4*)bp)[1];
            nb2 = ((const uint4*)bp)[2]; nb3 = ((const uint4*)bp)[3];
        }
        __syncthreads();
        #pragma unroll
        for (int ks = 0; ks < 2; ++ks) {
            bf16x8 am[4], bn[2];
            #pragma unroll
            for (int i = 0; i < 4; ++i)
                am[i] = *(const bf16x8*)&As[cur][i*16 + ln][ks*32 + quad*8];
            #pragma unroll
            for (int i = 0; i < 2; ++i)
                bn[i] = *(const bf16x8*)&Bs[cur][wave*32 + i*16 + ln][ks*32 + quad*8];
            #pragma unroll
            for (int mi = 0; mi < 4; ++mi)
                #pragma unroll
                for (int ni = 0; ni < 2; ++ni)
                    acc[mi][ni] = __builtin_amdgcn_mfma_f32_16x16x32_bf16(
                        am[mi], bn[ni], acc[mi][ni], 0,0,0);
        }
        a0 = na0; a1 = na1;
        b0 = nb0; b1 = nb1; b2 = nb2; b3 = nb3;
    }

    #pragma unroll
    for (int mi = 0; mi < 4; ++mi)
        #pragma unroll
        for (int ni = 0; ni < 2; ++ni) {
            int row = mt0*64 + mi*16 + quad*4;
            int col = nt0*128 + wave*32 + ni*16 + ln;
            float bv = bias[col];
            #pragma unroll
            for (int r = 0; r < 4; ++r)
                out[(size_t)(row + r)*1024 + col] = acc[mi][ni][r] + bv;
        }
}

// ---------------------------------------------------------------------------
extern "C" void kernel_launch(void* const* d_in, const int* in_sizes, int n_in,
                              void* d_out, int out_size, void* d_ws, size_t ws_size,
                              hipStream_t stream)
{
    const float* Q   = (const float*)d_in[0];
    const float* K   = (const float*)d_in[1];
    const float* V   = (const float*)d_in[2];
    const float* Wo  = (const float*)d_in[3];
    const float* Wb  = (const float*)d_in[4];
    const int* maskp = (const int*)d_in[5];
    float* out = (float*)d_out;

    // workspace layout (ushort units)
    unsigned short* Kf   = (unsigned short*)d_ws;              // 8.39 MB
    unsigned short* Vf   = Kf  + (size_t)B_*S_*D_;             // 8.39 MB
    unsigned short* Wob  = Vf  + (size_t)B_*S_*D_;             // 2.10 MB
    unsigned short* ctxb = Wob + (size_t)D_*D_;                // 8.39 MB
    float* Pv = (float*)(ctxb + (size_t)B_*S_*D_);             // 0.26 MB

    prep_kernel<<<3072, 256, 0, stream>>>(K, V, Wo, Kf, Vf, Wob, Pv);
    attn_kernel<<<512, 256, 0, stream>>>(Q, Kf, Vf, Pv, ctxb, maskp);
    proj_kernel<<<dim3(8, 64), 256, 0, stream>>>(ctxb, Wob, Wb, out);
}

// Round 3
// 147.871 us; speedup vs baseline: 1.2139x; 1.0031x over previous
//
#include <hip/hip_runtime.h>
#include <hip/hip_bf16.h>
#include <stdint.h>

// Problem constants
#define B_  2
#define S_  2048
#define D_  1024
#define H_  16
#define DQ_ 64
#define QT_ (S_/64)   // 32 q-tiles (64 rows each) per (b,h)
#define FMAX_ 16.0f   // fixed softmax max: logits ~ N(0,1)/sqrt64 -> max ~5.5 << 16

// exp(x*0.125 - FMAX) == exp2(x*C1 + C0)
#define C1_ 0.18033688011112042f   // 0.125 * log2(e)
#define C0_ (-23.083120654223414f) // -16  * log2(e)

typedef float f32x4  __attribute__((ext_vector_type(4)));
typedef float f32x16 __attribute__((ext_vector_type(16)));
typedef short bf16x8 __attribute__((ext_vector_type(8)));

__device__ __forceinline__ unsigned short f2bf(float f) {
    uint32_t u = __float_as_uint(f);
    u += 0x7fffu + ((u >> 16) & 1u);   // round-to-nearest-even
    return (unsigned short)(u >> 16);
}
__device__ __forceinline__ float bf2f(unsigned short u) {
    return __uint_as_float(((uint32_t)u) << 16);
}
__device__ __forceinline__ bf16x8 packbf8(float4 a, float4 b) {
    bf16x8 r;
    r[0]=(short)f2bf(a.x); r[1]=(short)f2bf(a.y);
    r[2]=(short)f2bf(a.z); r[3]=(short)f2bf(a.w);
    r[4]=(short)f2bf(b.x); r[5]=(short)f2bf(b.y);
    r[6]=(short)f2bf(b.z); r[7]=(short)f2bf(b.w);
    return r;
}
__device__ __forceinline__ float fast_exp2(float x) {
#if __has_builtin(__builtin_amdgcn_exp2f)
    return __builtin_amdgcn_exp2f(x);
#else
    float r; asm("v_exp_f32 %0, %1" : "=v"(r) : "v"(x)); return r;
#endif
}
__device__ __forceinline__ uint32_t cvt_pk_bf16(float lo, float hi) {
    uint32_t r;
    asm("v_cvt_pk_bf16_f32 %0, %1, %2" : "=v"(r) : "v"(lo), "v"(hi));
    return r;
}
// vdst[32..63] <-> vsrc[0..31]
__device__ __forceinline__ void permlane32_swap(uint32_t &a, uint32_t &b) {
    asm volatile("v_permlane32_swap_b32 %0, %1" : "+v"(a), "+v"(b));
}

// ---------------------------------------------------------------------------
// Kernel 1: prep. Emits K and V in EXACT 32x32x16-MFMA fragment order via an
// LDS-staged tile transpose so BOTH the global loads (row-segmented float4,
// 16 cache lines / wave-instr) and the fragment stores (consecutive tid ->
// consecutive 16B) are fully coalesced. Also Wo fp32->bf16 and Pv column
// partials (row-0 mean(V)). Grid 3072 x 256:
//   [0,1024)    : Vf fragments + Pv   (g = blk>>5, j = blk&31)
//   [1024,2048) : Kf fragments
//   [2048,3072) : Wo convert
// Kf frag fb = wk*4+s : lane l holds K[j*64+wk*32+(l&31)][s*16+(l>>5)*8 + 0..7]
// Vf frag fb = s*2+kk : lane l holds V[j*64+s*16+(l>>5)*8 + 0..7][kk*32+(l&31)]
// ---------------------------------------------------------------------------
__global__ __launch_bounds__(256) void prep_kernel(
    const float* __restrict__ K, const float* __restrict__ V,
    const float* __restrict__ W,
    unsigned short* __restrict__ Kf, unsigned short* __restrict__ Vf,
    unsigned short* __restrict__ Wb, float* __restrict__ Pv)
{
    __shared__ unsigned short Ls[64][72];
    __shared__ float Pp[8][64];
    const int blk = blockIdx.x, tid = threadIdx.x;

    if (blk < 2048) {
        const bool isV = blk < 1024;
        const int gb = isV ? blk : (blk - 1024);
        const int g = gb >> 5, j = gb & 31;
        const int b = g >> 4, h = g & 15;
        const float* src0 = (isV ? V : K) + ((size_t)(b*S_ + j*64))*D_ + h*64;

        // phase A: coalesced tile load (64 rows x 64 cols fp32) -> bf16 LDS
        {
            int row = tid >> 2, col0 = (tid & 3) * 16;
            const float* src = src0 + (size_t)row*D_ + col0;
            float4 f0 = ((const float4*)src)[0];
            float4 f1 = ((const float4*)src)[1];
            float4 f2 = ((const float4*)src)[2];
            float4 f3 = ((const float4*)src)[3];
            unsigned short* d = &Ls[row][col0];
            d[0]=f2bf(f0.x); d[1]=f2bf(f0.y); d[2]=f2bf(f0.z); d[3]=f2bf(f0.w);
            d[4]=f2bf(f1.x); d[5]=f2bf(f1.y); d[6]=f2bf(f1.z); d[7]=f2bf(f1.w);
            d[8]=f2bf(f2.x); d[9]=f2bf(f2.y); d[10]=f2bf(f2.z); d[11]=f2bf(f2.w);
            d[12]=f2bf(f3.x); d[13]=f2bf(f3.y); d[14]=f2bf(f3.z); d[15]=f2bf(f3.w);
        }
        __syncthreads();

        if (isV) {
            // phase B: transpose via LDS scalar reads -> coalesced frag stores
            #pragma unroll
            for (int ps = 0; ps < 2; ++ps) {
                const int slot = tid + ps*256;
                const int fb = slot >> 6, l = slot & 63;
                const int s = fb >> 1, kk = fb & 1;
                const int hi = l >> 5, l31 = l & 31;
                const int dcol = kk*32 + l31;
                unsigned short us[8];
                float p = 0.f;
                #pragma unroll
                for (int r = 0; r < 8; ++r) {
                    unsigned short u = Ls[s*16 + hi*8 + r][dcol];
                    us[r] = u;
                    p += bf2f(u);
                }
                *(uint4*)(Vf + ((size_t)gb*8 + fb)*512 + (size_t)l*8) = *(uint4*)us;
                Pp[s*2 + hi][dcol] = p;
            }
            __syncthreads();
            if (tid < 64) {
                float t = 0.f;
                #pragma unroll
                for (int i = 0; i < 8; ++i) t += Pp[i][tid];
                Pv[((size_t)g*64 + tid)*32 + j] = t;
            }
        } else {
            // phase B: rows are fragment-contiguous -> b128 LDS reads
            #pragma unroll
            for (int ps = 0; ps < 2; ++ps) {
                const int slot = tid + ps*256;
                const int fb = slot >> 6, l = slot & 63;
                const int wk = fb >> 2, s = fb & 3;
                const int hi = l >> 5, l31 = l & 31;
                uint4 val = *(const uint4*)&Ls[wk*32 + l31][s*16 + hi*8];
                *(uint4*)(Kf + ((size_t)gb*8 + fb)*512 + (size_t)l*8) = val;
            }
        }
    } else {
        int i = (blk - 2048)*256 + tid;     // < D*D/4 = 262144
        float4 f = ((const float4*)W)[i];
        ushort4 o;
        o.x = f2bf(f.x); o.y = f2bf(f.y); o.z = f2bf(f.z); o.w = f2bf(f.w);
        ((ushort4*)Wb)[i] = o;
    }
}

// ---------------------------------------------------------------------------
// Kernel 2: flash attention, 32x32x16 MFMA, ZERO-LDS main loop.
// Block = 256 thr = 4 waves: wave (wq,wk) owns q-rows [wq*32,+32) x keys
// [wk*32,+32) of each 64-key tile. K/V fragments loaded straight from the
// prearranged Kf/Vf (coalesced 1KB/instr), P kept in-register via
// cvt_pk_bf16 + v_permlane32_swap_b32. No barriers inside the j-loop; each
// wave uses its own niter (fully-masked diagonal waves skip free).
// Cross-wk O/l reduction through LDS once per pass.
// Grid 512: g = bid&31 (h + 16*b), pa = bid>>5 in [0,16); in-block pass
// pairing {pa, 31-pa} -> 33 iters/block, uniform. bid%8 = g%8 -> all blocks
// of a head-group on one XCD (K/V/Q ~1MB/group stays in L2).
// Row q=0 (fully masked -> mean(V)) from Pv by pa==0.
// ---------------------------------------------------------------------------
__global__ __launch_bounds__(256, 2) void attn_kernel(
    const float* __restrict__ Q,
    const unsigned short* __restrict__ Kf,
    const unsigned short* __restrict__ Vf,
    const float* __restrict__ Pv,
    unsigned short* __restrict__ ctx,
    const int* __restrict__ maskp)
{
    __shared__ float Osum[2][32][68];   // [wq][q][d] partial O from wk=1
    __shared__ float Lsum[2][32];       // [wq][q]    partial l from wk=1

    const int bid = blockIdx.x;
    const int g = bid & 31, pa = bid >> 5;
    const int h = g & 15, b = g >> 4;
    const int tid  = threadIdx.x;
    const int wave = tid >> 6, lane = tid & 63;
    const int wq = wave >> 1, wk = wave & 1;
    const int hi = lane >> 5, l31 = lane & 31;
    const int maskv = maskp[0];

    // fused mean(V) -> ctx row 0, cols [h*64, h*64+64)
    if (maskv && pa == 0 && tid < 64) {
        const float* p = Pv + ((size_t)g*64 + tid)*32;
        float s = 0.f;
        #pragma unroll
        for (int i = 0; i < 32; ++i) s += p[i];
        ctx[(size_t)b*S_*D_ + h*64 + tid] = f2bf(s * (1.0f/S_));
    }

    // fragment bases (advance by j*8*512 per tile)
    const unsigned short* kfb =
        Kf + ((size_t)g*32*8 + wk*4)*512 + (size_t)lane*8;
    const unsigned short* vfb =
        Vf + ((size_t)g*32*8 + wk*4)*512 + (size_t)lane*8;

    for (int t = 0; t < 2; ++t) {
        const int qt = t ? (31 - pa) : pa;
        int njw = maskv ? (qt + 1) : QT_;
        if (maskv && wq == 0 && wk == 1) njw = qt;  // diagonal tile fully masked

        // Q fragments: fp32 global -> bf16 registers (read once per pass)
        const int q0 = qt*64 + wq*32 + l31;
        const float* qrow = Q + ((size_t)(b*S_ + q0))*D_ + h*64;
        bf16x8 qf[4];
        #pragma unroll
        for (int s = 0; s < 4; ++s) {
            float4 f0 = ((const float4*)(qrow + s*16 + hi*8))[0];
            float4 f1 = ((const float4*)(qrow + s*16 + hi*8))[1];
            qf[s] = packbf8(f0, f1);
        }

        f32x16 o[2] = {};          // o[kk2]: d-halves of wave's 32q x 64d
        float lsum = 0.f;

        bf16x8 kc[4], vc[4], kn[4], vn[4];
        const unsigned short* kfj = kfb;
        const unsigned short* vfj = vfb;
        if (njw > 0) {
            #pragma unroll
            for (int s = 0; s < 4; ++s) {
                kc[s] = *(const bf16x8*)(kfj + s*512);
                vc[s] = *(const bf16x8*)(vfj + s*512);
            }
        }

        for (int j = 0; j < njw; ++j) {
            if (j + 1 < njw) {
                const unsigned short* kp = kfj + 8*512;
                const unsigned short* vp = vfj + 8*512;
                #pragma unroll
                for (int s = 0; s < 4; ++s) {
                    kn[s] = *(const bf16x8*)(kp + s*512);
                    vn[s] = *(const bf16x8*)(vp + s*512);
                }
            }

            // ---- S^T = K Q^T : lane holds col q=l31, rows key=(r&3)+8*(r>>2)+4*hi
            f32x16 st = {};
            #pragma unroll
            for (int s = 0; s < 4; ++s)
                st = __builtin_amdgcn_mfma_f32_32x32x16_bf16(kc[s], qf[s], st, 0,0,0);

            // ---- P = exp2(C1*S + C0), diagonal mask, accumulate l ----
            const bool diag = maskv && (j == qt) && (wk == wq);
            float e[16];
            #pragma unroll
            for (int r = 0; r < 16; ++r) {
                float ev = fast_exp2(fmaf(st[r], C1_, C0_));
                if (diag) {
                    int kr = (r&3) + 8*(r>>2) + 4*hi;   // key off == q off frame
                    ev = (kr >= l31) ? 0.f : ev;
                }
                e[r] = ev;
                lsum += ev;
            }

            // ---- pack P -> A-fragments in-register (cvt_pk + permlane swaps)
            uint32_t p01 = cvt_pk_bf16(e[0], e[1]);
            uint32_t p23 = cvt_pk_bf16(e[2], e[3]);
            uint32_t p45 = cvt_pk_bf16(e[4], e[5]);
            uint32_t p67 = cvt_pk_bf16(e[6], e[7]);
            permlane32_swap(p01, p45);
            permlane32_swap(p23, p67);
            uint32_t r01 = cvt_pk_bf16(e[8],  e[9]);
            uint32_t r23 = cvt_pk_bf16(e[10], e[11]);
            uint32_t r45 = cvt_pk_bf16(e[12], e[13]);
            uint32_t r67 = cvt_pk_bf16(e[14], e[15]);
            permlane32_swap(r01, r45);
            permlane32_swap(r23, r67);
            union { uint32_t u[4]; bf16x8 v; } pa0, pa1;
            pa0.u[0]=p01; pa0.u[1]=p23; pa0.u[2]=p45; pa0.u[3]=p67;  // keys 0..15
            pa1.u[0]=r01; pa1.u[1]=r23; pa1.u[2]=r45; pa1.u[3]=r67;  // keys 16..31

            // ---- O += P V ----
            o[0] = __builtin_amdgcn_mfma_f32_32x32x16_bf16(pa0.v, vc[0], o[0], 0,0,0);
            o[1] = __builtin_amdgcn_mfma_f32_32x32x16_bf16(pa0.v, vc[1], o[1], 0,0,0);
            o[0] = __builtin_amdgcn_mfma_f32_32x32x16_bf16(pa1.v, vc[2], o[0], 0,0,0);
            o[1] = __builtin_amdgcn_mfma_f32_32x32x16_bf16(pa1.v, vc[3], o[1], 0,0,0);

            #pragma unroll
            for (int s = 0; s < 4; ++s) { kc[s] = kn[s]; vc[s] = vn[s]; }
            kfj += 8*512; vfj += 8*512;
        }

        // ---- cross-wk reduction + epilogue ----
        lsum += __shfl_xor(lsum, 32);   // combine hi/lo key quads: l for q=l31

        if (wk == 1) {
            #pragma unroll
            for (int r = 0; r < 16; ++r) {
                int qr = (r&3) + 8*(r>>2) + 4*hi;
                Osum[wq][qr][l31]      = o[0][r];
                Osum[wq][qr][32 + l31] = o[1][r];
            }
            if (hi == 0) Lsum[wq][l31] = lsum;
        }
        __syncthreads();
        if (wk == 0) {
            float inv = 1.0f / (lsum + Lsum[wq][l31]);   // inv for q = l31
            #pragma unroll
            for (int r = 0; r < 16; ++r) {
                int qr = (r&3) + 8*(r>>2) + 4*hi;
                float o0v = o[0][r] + Osum[wq][qr][l31];
                float o1v = o[1][r] + Osum[wq][qr][32 + l31];
                float invr = __shfl(inv, qr);
                int q = qt*64 + wq*32 + qr;
                if (!(maskv && q == 0)) {   // row 0 = mean(V), done above
                    size_t base = ((size_t)(b*S_ + q))*D_ + h*64;
                    ctx[base + l31]      = f2bf(o0v * invr);
                    ctx[base + 32 + l31] = f2bf(o1v * invr);
                }
            }
        }
        __syncthreads();   // Osum/Lsum reused next pass
    }
}

// ---------------------------------------------------------------------------
// Kernel 3: out = ctx @ Wo^T + bias   (M=4096, N=1024, K=1024, bf16 MFMA)
// 64x128 tile, 4 waves (each 64x32), BK=64, double-buffered, 1 barrier/kt.
// Grid (8, 64) = 512 blocks -> 2 blocks/CU; bid%8 = nt0 -> each XCD caches
// exactly one 128-col Wo panel (0.25 MB).
// ---------------------------------------------------------------------------
__global__ __launch_bounds__(256, 2) void proj_kernel(
    const unsigned short* __restrict__ A,    // ctx bf16 [4096][1024]
    const unsigned short* __restrict__ Bw,   // Wo bf16  [1024][1024]
    const float* __restrict__ bias,
    float* __restrict__ out)
{
    __shared__ unsigned short As[2][64][72];
    __shared__ unsigned short Bs[2][128][72];
    const int nt0 = blockIdx.x;   // 0..7   (N panel)
    const int mt0 = blockIdx.y;   // 0..63  (M panel)
    const int tid  = threadIdx.x;
    const int wave = tid >> 6, lane = tid & 63;
    const int quad = lane >> 4, ln = lane & 15;

    const int arow = tid >> 2, acol = (tid & 3)*16;   // A: 64 rows x 64 cols
    const int brow = tid >> 1, bcol = (tid & 1)*32;   // B: 128 rows x 64 cols
    const unsigned short* aptr = A  + ((size_t)(mt0*64  + arow)*1024 + acol);
    const unsigned short* bptr = Bw + ((size_t)(nt0*128 + brow)*1024 + bcol);

    uint4 a0 = ((const uint4*)aptr)[0], a1 = ((const uint4*)aptr)[1];
    uint4 b0 = ((const uint4*)bptr)[0], b1 = ((const uint4*)bptr)[1],
          b2 = ((const uint4*)bptr)[2], b3 = ((const uint4*)bptr)[3];

    f32x4 acc[4][2] = {};

    for (int kt = 0; kt < 16; ++kt) {
        const int cur = kt & 1;
        *((uint4*)&As[cur][arow][acol])    = a0;
        *((uint4*)&As[cur][arow][acol+8])  = a1;
        *((uint4*)&Bs[cur][brow][bcol])    = b0;
        *((uint4*)&Bs[cur][brow][bcol+8])  = b1;
        *((uint4*)&Bs[cur][brow][bcol+16]) = b2;
        *((uint4*)&Bs[cur][brow][bcol+24]) = b3;
        uint4 na0, na1, nb0, nb1, nb2, nb3;
        if (kt < 15) {
            const unsigned short* ap = aptr + (kt+1)*64;
            const unsigned short* bp = bptr + (kt+1)*64;
            na0 = ((const uint4*)ap)[0]; na1 = ((const uint4*)ap)[1];
            nb0 = ((const uint4*)bp)[0]; nb1 = ((const uint4*)bp)[1];
            nb2 = ((const uint4*)bp)[2]; nb3 = ((const uint4*)bp)[3];
        }
        __syncthreads();
        #pragma unroll
        for (int ks = 0; ks < 2; ++ks) {
            bf16x8 am[4], bn[2];
            #pragma unroll
            for (int i = 0; i < 4; ++i)
                am[i] = *(const bf16x8*)&As[cur][i*16 + ln][ks*32 + quad*8];
            #pragma unroll
            for (int i = 0; i < 2; ++i)
                bn[i] = *(const bf16x8*)&Bs[cur][wave*32 + i*16 + ln][ks*32 + quad*8];
            #pragma unroll
            for (int mi = 0; mi < 4; ++mi)
                #pragma unroll
                for (int ni = 0; ni < 2; ++ni)
                    acc[mi][ni] = __builtin_amdgcn_mfma_f32_16x16x32_bf16(
                        am[mi], bn[ni], acc[mi][ni], 0,0,0);
        }
        a0 = na0; a1 = na1;
        b0 = nb0; b1 = nb1; b2 = nb2; b3 = nb3;
    }

    #pragma unroll
    for (int mi = 0; mi < 4; ++mi)
        #pragma unroll
        for (int ni = 0; ni < 2; ++ni) {
            int row = mt0*64 + mi*16 + quad*4;
            int col = nt0*128 + wave*32 + ni*16 + ln;
            float bv = bias[col];
            #pragma unroll
            for (int r = 0; r < 4; ++r)
                out[(size_t)(row + r)*1024 + col] = acc[mi][ni][r] + bv;
        }
}

// ---------------------------------------------------------------------------
extern "C" void kernel_launch(void* const* d_in, const int* in_sizes, int n_in,
                              void* d_out, int out_size, void* d_ws, size_t ws_size,
                              hipStream_t stream)
{
    const float* Q   = (const float*)d_in[0];
    const float* K   = (const float*)d_in[1];
    const float* V   = (const float*)d_in[2];
    const float* Wo  = (const float*)d_in[3];
    const float* Wb  = (const float*)d_in[4];
    const int* maskp = (const int*)d_in[5];
    float* out = (float*)d_out;

    // workspace layout (ushort units)
    unsigned short* Kf   = (unsigned short*)d_ws;              // 8.39 MB
    unsigned short* Vf   = Kf  + (size_t)B_*S_*D_;             // 8.39 MB
    unsigned short* Wob  = Vf  + (size_t)B_*S_*D_;             // 2.10 MB
    unsigned short* ctxb = Wob + (size_t)D_*D_;                // 8.39 MB
    float* Pv = (float*)(ctxb + (size_t)B_*S_*D_);             // 0.26 MB

    prep_kernel<<<3072, 256, 0, stream>>>(K, V, Wo, Kf, Vf, Wob, Pv);
    attn_kernel<<<512, 256, 0, stream>>>(Q, Kf, Vf, Pv, ctxb, maskp);
    proj_kernel<<<dim3(8, 64), 256, 0, stream>>>(ctxb, Wob, Wb, out);
}